// Round 3
// baseline (461.661 us; speedup 1.0000x reference)
//
#include <hip/hip_runtime.h>
#include <stdint.h>

// Problem constants
#define B_    64
#define N_    512
#define DIM_  256
#define H_    8
#define DH_   64
#define INNER_ 512

typedef __attribute__((ext_vector_type(8))) short bf16x8;
typedef __attribute__((ext_vector_type(4))) float f32x4;
typedef __attribute__((ext_vector_type(4))) short s16x4;

__device__ __forceinline__ short f2bf(float f) {
  unsigned int u = __float_as_uint(f);
  u += 0x7fffu + ((u >> 16) & 1u);          // RNE
  return (short)(u >> 16);
}
__device__ __forceinline__ float bf2f(short s) {
  return __uint_as_float(((unsigned int)(unsigned short)s) << 16);
}

// ---------------------------------------------------------------------------
// Prep: fp32 -> bf16 edge conversions.
//  Wt1[2048][256] bf16: rows 0..511 = Wq cols, 512..1535 = Wkv cols,
//                       1536..2047 = Wg cols  (B^T layout for GEMM1)
//  WoT[256][512] bf16 = Wo^T                  (B^T layout for GEMM3)
//  xb  [32768*256] bf16 = x flat
// ---------------------------------------------------------------------------
#define PREP_WT1  (2048 * 256)
#define PREP_WOT  (256 * 512)
#define PREP_X    (32768 * 256)
#define PREP_TOT  (PREP_WT1 + PREP_WOT + PREP_X)

__global__ void prep_k(const float* __restrict__ x,
                       const float* __restrict__ Wq, const float* __restrict__ Wkv,
                       const float* __restrict__ Wg, const float* __restrict__ Wo,
                       short* __restrict__ Wt1, short* __restrict__ WoT,
                       short* __restrict__ xb)
{
  const int idx = blockIdx.x * 256 + threadIdx.x;
  if (idx < PREP_WT1) {
    const int n = idx >> 8, k = idx & 255;
    float v;
    if (n < 512)        v = Wq[k * 512 + n];
    else if (n < 1536)  v = Wkv[k * 1024 + (n - 512)];   // K cols then V cols
    else                v = Wg[k * 512 + (n - 1536)];
    Wt1[idx] = f2bf(v);
  } else if (idx < PREP_WT1 + PREP_WOT) {
    const int j = idx - PREP_WT1;
    const int n = j >> 9, k = j & 511;
    WoT[j] = f2bf(Wo[k * 256 + n]);
  } else if (idx < PREP_TOT) {
    const int j = idx - (PREP_WT1 + PREP_WOT);
    xb[j] = f2bf(x[j]);
  }
}

// ---------------------------------------------------------------------------
// GEMM1: C = xb[32768,256] @ Wt1^T  (N=2048 fused Q|K|V|G), all bf16.
// 128x128 tile, BK=32, 4 waves (2x2), each wave 4x4 MFMA 16x16x32 tiles.
// Explicit staging: lane (ric=lane>>2, cslot=lane&3) loads 16B chunk cslot of
// row rr+ric, stores to LDS slot cslot ^ ((ric>>1)&3). Read side fetches
// chunk q from slot q ^ ((m>>1)&3).
// ---------------------------------------------------------------------------
__global__ __launch_bounds__(256, 2) void gemm_qkvg(
    const short* __restrict__ X, const short* __restrict__ Wt,
    const float* __restrict__ bg,
    short* __restrict__ Q, short* __restrict__ Kb,
    short* __restrict__ Vt, short* __restrict__ G)
{
  __shared__ __align__(16) short As[128 * 32];
  __shared__ __align__(16) short Bs[128 * 32];
  const int tid = threadIdx.x;
  const int w = tid >> 6, lane = tid & 63;
  const int m = lane & 15, q = lane >> 4;
  const int m0 = blockIdx.x * 128, n0 = blockIdx.y * 128;
  const int ric = lane >> 2, cslot = lane & 3;
  const int sslot = cslot ^ ((ric >> 1) & 3);   // swizzled LDS 16B-slot
  const int wr = (w >> 1) * 64, wc = (w & 1) * 64;
  const int rsw = (m >> 1) & 3;                 // read-side swizzle
  f32x4 acc[4][4] = {};
  for (int k0 = 0; k0 < DIM_; k0 += 32) {
    bf16x8 va[2], vb[2];
#pragma unroll
    for (int s = 0; s < 2; ++s) {
      const int rr = w * 32 + s * 16;
      va[s] = *(const bf16x8*)&X [(size_t)(m0 + rr + ric) * DIM_ + k0 + cslot * 8];
      vb[s] = *(const bf16x8*)&Wt[(size_t)(n0 + rr + ric) * DIM_ + k0 + cslot * 8];
    }
    __syncthreads();                            // prev iter's LDS reads done
#pragma unroll
    for (int s = 0; s < 2; ++s) {
      const int rr = w * 32 + s * 16;
      *(bf16x8*)&As[(rr + ric) * 32 + sslot * 8] = va[s];
      *(bf16x8*)&Bs[(rr + ric) * 32 + sslot * 8] = vb[s];
    }
    __syncthreads();
    bf16x8 af[4], bfv[4];
#pragma unroll
    for (int t = 0; t < 4; ++t) {
      af[t]  = *(const bf16x8*)&As[(wr + t * 16 + m) * 32 + ((q ^ rsw) * 8)];
      bfv[t] = *(const bf16x8*)&Bs[(wc + t * 16 + m) * 32 + ((q ^ rsw) * 8)];
    }
#pragma unroll
    for (int ti = 0; ti < 4; ++ti)
#pragma unroll
      for (int tj = 0; tj < 4; ++tj)
        acc[ti][tj] = __builtin_amdgcn_mfma_f32_16x16x32_bf16(af[ti], bfv[tj], acc[ti][tj], 0, 0, 0);
  }
  // Epilogue: route by region. C/D layout: col = lane&15, row = q*4 + reg.
  const int region = blockIdx.y >> 2;           // 0=Q 1=K 2=V 3=G
  const int cb = (n0 & 511) + wc;
#pragma unroll
  for (int ti = 0; ti < 4; ++ti) {
    const int mgb = m0 + wr + ti * 16 + q * 4;  // global row base (4 rows)
    const int b = mgb >> 9, n = mgb & 511;
#pragma unroll
    for (int tj = 0; tj < 4; ++tj) {
      const int c = cb + tj * 16 + m;           // col within region [0,512)
      const int h = c >> 6, d = c & 63;
      if (region == 2) {                        // V -> transposed [B,H,DH,N]
        s16x4 st;
#pragma unroll
        for (int r = 0; r < 4; ++r) st[r] = f2bf(acc[ti][tj][r]);
        *(s16x4*)&Vt[((size_t)(b * 8 + h) * 64 + d) * 512 + n] = st;
      } else if (region == 0) {
#pragma unroll
        for (int r = 0; r < 4; ++r)
          Q[((size_t)(b * 8 + h) * 512 + (n + r)) * 64 + d] = f2bf(acc[ti][tj][r]);
      } else if (region == 1) {
#pragma unroll
        for (int r = 0; r < 4; ++r)
          Kb[((size_t)(b * 8 + h) * 512 + (n + r)) * 64 + d] = f2bf(acc[ti][tj][r]);
      } else {                                  // gates = x@Wg + bg, [32768,512]
        const float bgv = bg[c];
#pragma unroll
        for (int r = 0; r < 4; ++r)
          G[(size_t)(mgb + r) * 512 + c] = f2bf(acc[ti][tj][r] + bgv);
      }
    }
  }
}

// ---------------------------------------------------------------------------
// Attention: one block = (b, h, 16-row Q tile). Scores in regs (wave owns 128
// j-cols), fp32 bias + mask in-reg, two-level row max/sum, deferred
// normalization, un-normalized P -> LDS in MFMA-A layout, PV with V^T from
// global. Gate multiply fused, writes OG in-place over G (bf16).
// ---------------------------------------------------------------------------
__global__ __launch_bounds__(256, 2) void attn_k(
    const short* __restrict__ Q, const short* __restrict__ K,
    const short* __restrict__ Vt, const float* __restrict__ bias,
    const int* __restrict__ mask, short* G)
{
  __shared__ __align__(16) short P[16 * 520];   // +8 pad elems/row
  __shared__ float wred[4][16];
  __shared__ float grow[16];
  const int tid = threadIdx.x;
  const int w = tid >> 6, lane = tid & 63;
  const int m = lane & 15, q = lane >> 4;
  const int bid = blockIdx.x;
  const int it = bid & 31, h = (bid >> 5) & 7, b = bid >> 8;
  const int i0 = it * 16;
  const size_t bh = (size_t)b * 8 + h;
  const short* Qp = Q + (bh * 512 + i0) * 64;
  const short* Kp = K + bh * 512 * 64;
  const short* Vp = Vt + bh * 64 * 512;

  // Q fragments: A-layout (row = lane&15, k = q*8+j), 2 k-chunks of 32
  bf16x8 qf0 = *(const bf16x8*)&Qp[m * 64 + q * 8];
  bf16x8 qf1 = *(const bf16x8*)&Qp[m * 64 + 32 + q * 8];

  const int jw = w * 128;                       // this wave's j-range
  f32x4 s[8];
#pragma unroll
  for (int t = 0; t < 8; ++t) {
    const int j0 = jw + t * 16;
    bf16x8 kf0 = *(const bf16x8*)&Kp[(j0 + m) * 64 + q * 8];
    bf16x8 kf1 = *(const bf16x8*)&Kp[(j0 + m) * 64 + 32 + q * 8];
    f32x4 a = {};
    a = __builtin_amdgcn_mfma_f32_16x16x32_bf16(qf0, kf0, a, 0, 0, 0);
    a = __builtin_amdgcn_mfma_f32_16x16x32_bf16(qf1, kf1, a, 0, 0, 0);
    s[t] = a;
  }
  int mi[4];
#pragma unroll
  for (int r = 0; r < 4; ++r) mi[r] = mask[b * 512 + i0 + q * 4 + r];
  const float NEG = -1e30f;                     // dominates any real score
  float rmax[4] = {NEG, NEG, NEG, NEG};
#pragma unroll
  for (int t = 0; t < 8; ++t) {
    const int j = jw + t * 16 + m;
    const int mj = mask[b * 512 + j];
    const float* bp = bias + (((size_t)h * 512 + i0 + q * 4) * 512) + j;
#pragma unroll
    for (int r = 0; r < 4; ++r) {
      float v = s[t][r] * 0.125f + bp[(size_t)r * 512];
      if (!(mi[r] && mj)) v = NEG;
      s[t][r] = v;
      rmax[r] = fmaxf(rmax[r], v);
    }
  }
#pragma unroll
  for (int off = 1; off < 16; off <<= 1)
#pragma unroll
    for (int r = 0; r < 4; ++r)
      rmax[r] = fmaxf(rmax[r], __shfl_xor(rmax[r], off, 64));
  if (m == 0) {
#pragma unroll
    for (int r = 0; r < 4; ++r) wred[w][q * 4 + r] = rmax[r];
  }
  __syncthreads();
  if (tid < 16)
    grow[tid] = fmaxf(fmaxf(wred[0][tid], wred[1][tid]),
                      fmaxf(wred[2][tid], wred[3][tid]));
  __syncthreads();
  float gmax[4];
#pragma unroll
  for (int r = 0; r < 4; ++r) gmax[r] = grow[q * 4 + r];
  float rsum[4] = {0.f, 0.f, 0.f, 0.f};
#pragma unroll
  for (int t = 0; t < 8; ++t) {
    const int j = jw + t * 16 + m;
#pragma unroll
    for (int r = 0; r < 4; ++r) {
      const float e = __expf(s[t][r] - gmax[r]);   // all-masked row -> e=1
      rsum[r] += e;
      P[(q * 4 + r) * 520 + j] = f2bf(e);          // un-normalized
    }
  }
#pragma unroll
  for (int off = 1; off < 16; off <<= 1)
#pragma unroll
    for (int r = 0; r < 4; ++r) rsum[r] += __shfl_xor(rsum[r], off, 64);
  __syncthreads();                                  // gmax reads + P writes done
  if (m == 0) {
#pragma unroll
    for (int r = 0; r < 4; ++r) wred[w][q * 4 + r] = rsum[r];
  }
  __syncthreads();
  if (tid < 16)
    grow[tid] = wred[0][tid] + wred[1][tid] + wred[2][tid] + wred[3][tid];
  __syncthreads();
  float gsum[4];
#pragma unroll
  for (int r = 0; r < 4; ++r) gsum[r] = grow[q * 4 + r];

  // PV: wave owns d-tile [w*16, w*16+16). A = P (LDS), B = V^T (global).
  f32x4 o = {};
  const int d0 = w * 16;
#pragma unroll
  for (int kc = 0; kc < 16; ++kc) {
    bf16x8 pf = *(const bf16x8*)&P[m * 520 + kc * 32 + q * 8];
    bf16x8 vf = *(const bf16x8*)&Vp[(d0 + m) * 512 + kc * 32 + q * 8];
    o = __builtin_amdgcn_mfma_f32_16x16x32_bf16(pf, vf, o, 0, 0, 0);
  }
  // Epilogue: normalize, gate, write OG in-place over G.
  const int c = h * 64 + d0 + m;
#pragma unroll
  for (int r = 0; r < 4; ++r) {
    const int i = i0 + q * 4 + r;
    const size_t addr = ((size_t)b * 512 + i) * 512 + c;
    const float gate = bf2f(G[addr]);
    G[addr] = f2bf((o[r] / gsum[r]) * gate);
  }
}

// ---------------------------------------------------------------------------
// GEMM3: out = OG[32768,512] @ Wo + bo   (B^T = WoT[256][512]); fp32 output.
// ---------------------------------------------------------------------------
__global__ __launch_bounds__(256, 2) void gemm_og(
    const short* __restrict__ A, const short* __restrict__ Bt,
    const float* __restrict__ bo, float* __restrict__ out)
{
  __shared__ __align__(16) short As[128 * 32];
  __shared__ __align__(16) short Bs[128 * 32];
  const int tid = threadIdx.x;
  const int w = tid >> 6, lane = tid & 63;
  const int m = lane & 15, q = lane >> 4;
  const int m0 = blockIdx.x * 128, n0 = blockIdx.y * 128;
  const int ric = lane >> 2, cslot = lane & 3;
  const int sslot = cslot ^ ((ric >> 1) & 3);
  const int wr = (w >> 1) * 64, wc = (w & 1) * 64;
  const int rsw = (m >> 1) & 3;
  f32x4 acc[4][4] = {};
  for (int k0 = 0; k0 < INNER_; k0 += 32) {
    bf16x8 va[2], vb[2];
#pragma unroll
    for (int s = 0; s < 2; ++s) {
      const int rr = w * 32 + s * 16;
      va[s] = *(const bf16x8*)&A [(size_t)(m0 + rr + ric) * INNER_ + k0 + cslot * 8];
      vb[s] = *(const bf16x8*)&Bt[(size_t)(n0 + rr + ric) * INNER_ + k0 + cslot * 8];
    }
    __syncthreads();
#pragma unroll
    for (int s = 0; s < 2; ++s) {
      const int rr = w * 32 + s * 16;
      *(bf16x8*)&As[(rr + ric) * 32 + sslot * 8] = va[s];
      *(bf16x8*)&Bs[(rr + ric) * 32 + sslot * 8] = vb[s];
    }
    __syncthreads();
    bf16x8 af[4], bfv[4];
#pragma unroll
    for (int t = 0; t < 4; ++t) {
      af[t]  = *(const bf16x8*)&As[(wr + t * 16 + m) * 32 + ((q ^ rsw) * 8)];
      bfv[t] = *(const bf16x8*)&Bs[(wc + t * 16 + m) * 32 + ((q ^ rsw) * 8)];
    }
#pragma unroll
    for (int ti = 0; ti < 4; ++ti)
#pragma unroll
      for (int tj = 0; tj < 4; ++tj)
        acc[ti][tj] = __builtin_amdgcn_mfma_f32_16x16x32_bf16(af[ti], bfv[tj], acc[ti][tj], 0, 0, 0);
  }
#pragma unroll
  for (int ti = 0; ti < 4; ++ti) {
    const int row = m0 + wr + ti * 16 + q * 4;
#pragma unroll
    for (int tj = 0; tj < 4; ++tj) {
      const int c = n0 + wc + tj * 16 + m;
      const float bov = bo[c];
#pragma unroll
      for (int r = 0; r < 4; ++r)
        out[(size_t)(row + r) * 256 + c] = acc[ti][tj][r] + bov;
    }
  }
}

// ---------------------------------------------------------------------------
extern "C" void kernel_launch(void* const* d_in, const int* in_sizes, int n_in,
                              void* d_out, int out_size, void* d_ws, size_t ws_size,
                              hipStream_t stream)
{
  (void)in_sizes; (void)n_in; (void)out_size; (void)ws_size;
  const float* x    = (const float*)d_in[0];
  const int*   mask = (const int*)d_in[1];
  const float* bias = (const float*)d_in[2];
  const float* Wq   = (const float*)d_in[3];
  const float* Wkv  = (const float*)d_in[4];
  const float* Wo   = (const float*)d_in[5];
  const float* bo   = (const float*)d_in[6];
  const float* Wg   = (const float*)d_in[7];
  const float* bg   = (const float*)d_in[8];
  float* out = (float*)d_out;

  char* ws = (char*)d_ws;
  size_t off = 0;
  short* Wt1 = (short*)(ws + off); off += (size_t)2048 * 256 * 2;         // 1.0 MiB
  short* WoT = (short*)(ws + off); off += (size_t)256 * 512 * 2;          // 0.25 MiB
  short* xb  = (short*)(ws + off); off += (size_t)32768 * 256 * 2;        // 16 MiB
  short* Qb  = (short*)(ws + off); off += (size_t)B_ * H_ * N_ * DH_ * 2; // 32 MiB
  short* Kb  = (short*)(ws + off); off += (size_t)B_ * H_ * N_ * DH_ * 2; // 32 MiB
  short* Vt  = (short*)(ws + off); off += (size_t)B_ * H_ * DH_ * N_ * 2; // 32 MiB
  short* G   = (short*)(ws + off); off += (size_t)B_ * N_ * INNER_ * 2;   // 32 MiB

  prep_k<<<(PREP_TOT + 255) / 256, 256, 0, stream>>>(x, Wq, Wkv, Wg, Wo, Wt1, WoT, xb);
  gemm_qkvg<<<dim3(256, 16), 256, 0, stream>>>(xb, Wt1, bg, Qb, Kb, Vt, G);
  attn_k<<<16384, 256, 0, stream>>>(Qb, Kb, Vt, bias, mask, G);
  gemm_og<<<dim3(256, 2), 256, 0, stream>>>(G, WoT, bo, out);
}